// Round 5
// baseline (195146.057 us; speedup 1.0000x reference)
//
#include <hip/hip_runtime.h>
#include <stdint.h>

// CharLSTM persistent-RNN kernel for MI355X. f32 in / f32 out.
// R9:  conflict-free fragment layout; tagged 64-bit h words (f32<<32 | step).
// R10: flag hierarchy: -6.5% -> concentration on 4 lines made queueing worse.
// R11: single-hop polling + x-dot overlap: neutral -> sync hops exonerated.
// R12: float4 fragments, ds_read_b128, DPP reduce: -3%; spill is L1-served.
// R13: s_sleep(2) poll backoff + single-line coalesced publish: -41% (73->43ms).
//      Per-line service contention CONFIRMED as the binding constraint.
// R14: halve the fan-out structurally: 128 WGs x 1024 threads (16 waves,
//      16 neurons/WG) instead of 256 x 512.
//        - per-line pollers: 2048 -> 1024 per round (1 owning thread/WG);
//          poll words/thread 4 -> 2 (shorter round body).
//        - publishers: 256 -> 128 coalesced publishes/step (2 lines each,
//          wave0 lanes 0-15).
//        - global max-skew candidates: 256 -> 128 WGs.
//        - logits duty balanced: EVERY WG's wave 1 owns one output column.
//      Compute per wave unchanged (1 neuron/wave). Idle CUs are free in a
//      latency-bound regime.

#define T_STEPS 16384
#define HID     2048
#define EMBD    512
#define NCH     128
#define FANIN   (EMBD + HID)
#define NBLK    128
#define TPB     1024
#define NEUR_PER_WG 16

static_assert(TPB == 2 * EMBD, "index math assumes TPB == 2*EMBD");
static_assert(NBLK * NEUR_PER_WG == HID, "neuron coverage");

__device__ __forceinline__ float sigmoid_f(float x) {
  return 1.0f / (1.0f + __expf(-x));
}
__device__ __forceinline__ float tanh_f(float x) {
  return 1.0f - 2.0f / (__expf(2.0f * x) + 1.0f);
}
__device__ __forceinline__ unsigned long long ld_agent64(const unsigned long long* p) {
  return __hip_atomic_load(p, __ATOMIC_RELAXED, __HIP_MEMORY_SCOPE_AGENT);
}
__device__ __forceinline__ void st_agent64(unsigned long long* p, unsigned long long v) {
  __hip_atomic_store(p, v, __ATOMIC_RELAXED, __HIP_MEMORY_SCOPE_AGENT);
}

// ---- VALU-only wave64 reduction: DPP row_shr tree + readlane of row tails ----
#define DPP_ROW_SHR(n) (0x110 | (n))
__device__ __forceinline__ float row_reduce(float x) {
  x += __int_as_float(__builtin_amdgcn_update_dpp(0, __float_as_int(x), DPP_ROW_SHR(1), 0xF, 0xF, true));
  x += __int_as_float(__builtin_amdgcn_update_dpp(0, __float_as_int(x), DPP_ROW_SHR(2), 0xF, 0xF, true));
  x += __int_as_float(__builtin_amdgcn_update_dpp(0, __float_as_int(x), DPP_ROW_SHR(4), 0xF, 0xF, true));
  x += __int_as_float(__builtin_amdgcn_update_dpp(0, __float_as_int(x), DPP_ROW_SHR(8), 0xF, 0xF, true));
  return x;  // lanes 15/31/47/63 hold their row's sum
}
__device__ __forceinline__ float wave_sum(float x) {
  const int xi = __float_as_int(row_reduce(x));
  return __int_as_float(__builtin_amdgcn_readlane(xi, 15))
       + __int_as_float(__builtin_amdgcn_readlane(xi, 31))
       + __int_as_float(__builtin_amdgcn_readlane(xi, 47))
       + __int_as_float(__builtin_amdgcn_readlane(xi, 63));
}

__global__ __launch_bounds__(TPB) void lstm_persist(
    const int* __restrict__ seq,
    const float* __restrict__ emb,
    const float* __restrict__ Wf, const float* __restrict__ bfv,
    const float* __restrict__ Wi, const float* __restrict__ biv,
    const float* __restrict__ Wg, const float* __restrict__ bgv,
    const float* __restrict__ Wo, const float* __restrict__ bov,
    const float* __restrict__ Wfc, const float* __restrict__ bfc,
    unsigned long long* __restrict__ hbuf,   // [2][HID] tagged h
    float* __restrict__ out)                 // f32: [T][NCH] logits, h[HID], c[HID]
{
  __shared__ __attribute__((aligned(16))) float h_lds[2][HID];
  __shared__ float hout[NEUR_PER_WG];   // per-step collected neuron outputs

  const int tid  = threadIdx.x;
  const int wv   = tid >> 6;
  const int lane = tid & 63;
  const int j    = blockIdx.x * NEUR_PER_WG + wv;   // neuron this wave owns

  // seq dtype guard (selects int32 on this data; kept for safety)
  int shift = 1;
  for (int k = 0; k < 64; ++k) {
    if (seq[2 * k + 1] != 0) { shift = 0; break; }
  }

  // ---- preload weights, float4 chunks: lane l owns cols {256k+4l..+3} ----
  const float* Wmat[4] = {Wf, Wi, Wg, Wo};
  const float* bvec[4] = {bfv, biv, bgv, bov};
  float4 wh4[4][8], wx4[4][2];
  float  bias[4];
  #pragma unroll
  for (int g = 0; g < 4; ++g) {
    const float* rp = Wmat[g] + (size_t)j * FANIN;
    const float4* hp4 = reinterpret_cast<const float4*>(rp + EMBD);
    const float4* xp4 = reinterpret_cast<const float4*>(rp);
    #pragma unroll
    for (int k = 0; k < 8; ++k) wh4[g][k] = hp4[k * 64 + lane];
    #pragma unroll
    for (int k = 0; k < 2; ++k) wx4[g][k] = xp4[k * 64 + lane];
    bias[g] = bvec[g][j];
  }

  // ---- logits duty: every WG's wave 1 owns one output column ----
  int lcol = -1;
  float4 wfc4[8];
  float bfc_c = 0.0f;
  if (wv == 1) {
    lcol = blockIdx.x;                      // 0..127
    const float4* wp4 = reinterpret_cast<const float4*>(Wfc + (size_t)lcol * HID);
    #pragma unroll
    for (int u = 0; u < 8; ++u) wfc4[u] = wp4[u * 64 + lane];
    bfc_c = bfc[lcol];
  }

  float creg = 0.0f;  // cell state (lane 0 only)
  const int i0 = tid, i1 = tid + TPB;       // 2 words per thread

  for (int t = 0; t < T_STEPS; ++t) {
    const int bsel = t & 1;
    const unsigned long long* src = hbuf + (size_t)bsel * HID;
    const unsigned ut = (unsigned)t;

    // ---- issue the 2 tagged h loads first (outstanding during x work) ----
    unsigned long long v0 = ld_agent64(src + i0), v1 = ld_agent64(src + i1);

    // ---- x loads (L2-resident emb row, float4 coalesced) ----
    const int s = seq[(size_t)t << shift];
    const float4* xr4 = reinterpret_cast<const float4*>(emb + (size_t)s * EMBD);
    const float4 xv0 = xr4[lane];
    const float4 xv1 = xr4[64 + lane];

    // ---- x-part of the gate dots: independent of h, hides h latency ----
    float a0 = 0.0f, a1 = 0.0f, a2 = 0.0f, a3 = 0.0f;
    #pragma unroll
    for (int k = 0; k < 2; ++k) {
      const float4 xv = (k == 0) ? xv0 : xv1;
      a0 = fmaf(wx4[0][k].x, xv.x, a0); a0 = fmaf(wx4[0][k].y, xv.y, a0);
      a0 = fmaf(wx4[0][k].z, xv.z, a0); a0 = fmaf(wx4[0][k].w, xv.w, a0);
      a1 = fmaf(wx4[1][k].x, xv.x, a1); a1 = fmaf(wx4[1][k].y, xv.y, a1);
      a1 = fmaf(wx4[1][k].z, xv.z, a1); a1 = fmaf(wx4[1][k].w, xv.w, a1);
      a2 = fmaf(wx4[2][k].x, xv.x, a2); a2 = fmaf(wx4[2][k].y, xv.y, a2);
      a2 = fmaf(wx4[2][k].z, xv.z, a2); a2 = fmaf(wx4[2][k].w, xv.w, a2);
      a3 = fmaf(wx4[3][k].x, xv.x, a3); a3 = fmaf(wx4[3][k].y, xv.y, a3);
      a3 = fmaf(wx4[3][k].z, xv.z, a3); a3 = fmaf(wx4[3][k].w, xv.w, a3);
    }

    // ---- single-hop readiness with s_sleep backoff ----
    while (((unsigned)v0 != ut) | ((unsigned)v1 != ut)) {
      __builtin_amdgcn_s_sleep(2);   // ~128 cyc: keep per-line request rate low
      if ((unsigned)v0 != ut) v0 = ld_agent64(src + i0);
      if ((unsigned)v1 != ut) v1 = ld_agent64(src + i1);
    }
    h_lds[bsel][i0] = __uint_as_float((unsigned)(v0 >> 32));
    h_lds[bsel][i1] = __uint_as_float((unsigned)(v1 >> 32));
    __syncthreads();

    // ---- h-part of the gate dots: 8x ds_read_b128, conflict-free ----
    const float4* hp4 = reinterpret_cast<const float4*>(&h_lds[bsel][0]);
    #pragma unroll
    for (int k = 0; k < 8; ++k) {
      const float4 hv = hp4[k * 64 + lane];
      a0 = fmaf(wh4[0][k].x, hv.x, a0); a0 = fmaf(wh4[0][k].y, hv.y, a0);
      a0 = fmaf(wh4[0][k].z, hv.z, a0); a0 = fmaf(wh4[0][k].w, hv.w, a0);
      a1 = fmaf(wh4[1][k].x, hv.x, a1); a1 = fmaf(wh4[1][k].y, hv.y, a1);
      a1 = fmaf(wh4[1][k].z, hv.z, a1); a1 = fmaf(wh4[1][k].w, hv.w, a1);
      a2 = fmaf(wh4[2][k].x, hv.x, a2); a2 = fmaf(wh4[2][k].y, hv.y, a2);
      a2 = fmaf(wh4[2][k].z, hv.z, a2); a2 = fmaf(wh4[2][k].w, hv.w, a2);
      a3 = fmaf(wh4[3][k].x, hv.x, a3); a3 = fmaf(wh4[3][k].y, hv.y, a3);
      a3 = fmaf(wh4[3][k].z, hv.z, a3); a3 = fmaf(wh4[3][k].w, hv.w, a3);
    }

    // ---- VALU-only reduction (no DS-pipe shfl) ----
    const float A0 = wave_sum(a0);
    const float A1 = wave_sum(a1);
    const float A2 = wave_sum(a2);
    const float A3 = wave_sum(a3);

    if (lane == 0) {
      const float fg = sigmoid_f(A0 + bias[0]);
      const float ig = sigmoid_f(A1 + bias[1]);
      const float gg = tanh_f(A2 + bias[2]);
      const float og = sigmoid_f(A3 + bias[3]);
      creg = fg * creg + ig * gg;
      const float hn = og * tanh_f(creg);
      hout[wv] = hn;                          // collect for coalesced publish
      if (t == T_STEPS - 1) {
        out[(size_t)T_STEPS * NCH + j]       = hn;     // final h
        out[(size_t)T_STEPS * NCH + HID + j] = creg;   // final c
      }
    }
    __syncthreads();   // hout[] complete

    // ---- coalesced publish: 2 full 64B lines by wave 0 lanes 0..15 ----
    if (wv == 0 && lane < NEUR_PER_WG) {
      const unsigned long long pk =
          ((unsigned long long)__float_as_uint(hout[lane]) << 32) |
          (unsigned long long)(unsigned)(t + 1);
      st_agent64(&hbuf[(size_t)((t + 1) & 1) * HID +
                       (size_t)blockIdx.x * NEUR_PER_WG + lane], pk);
    }

    // ---- logits for step t-1 from already-staged h[t] (rides in wait slack) ----
    if (lcol >= 0 && t > 0) {
      const float4* hq4 = reinterpret_cast<const float4*>(&h_lds[bsel][0]);
      float sacc = 0.0f;
      #pragma unroll
      for (int u = 0; u < 8; ++u) {
        const float4 hv = hq4[u * 64 + lane];
        sacc = fmaf(wfc4[u].x, hv.x, sacc); sacc = fmaf(wfc4[u].y, hv.y, sacc);
        sacc = fmaf(wfc4[u].z, hv.z, sacc); sacc = fmaf(wfc4[u].w, hv.w, sacc);
      }
      const float S = wave_sum(sacc);
      if (lane == 0) out[(size_t)(t - 1) * NCH + lcol] = S + bfc_c;
    }
  }

  // ---- epilogue: stage h[T] (tag T, slot 0) and emit logits for t = T-1 ----
  {
    const unsigned long long* src = hbuf;  // T_STEPS & 1 == 0
    const unsigned ut = (unsigned)T_STEPS;
    unsigned long long v0 = ld_agent64(src + i0), v1 = ld_agent64(src + i1);
    while (((unsigned)v0 != ut) | ((unsigned)v1 != ut)) {
      __builtin_amdgcn_s_sleep(2);
      if ((unsigned)v0 != ut) v0 = ld_agent64(src + i0);
      if ((unsigned)v1 != ut) v1 = ld_agent64(src + i1);
    }
    h_lds[0][i0] = __uint_as_float((unsigned)(v0 >> 32));
    h_lds[0][i1] = __uint_as_float((unsigned)(v1 >> 32));
    __syncthreads();
    if (lcol >= 0) {
      const float4* hq4 = reinterpret_cast<const float4*>(&h_lds[0][0]);
      float sacc = 0.0f;
      #pragma unroll
      for (int u = 0; u < 8; ++u) {
        const float4 hv = hq4[u * 64 + lane];
        sacc = fmaf(wfc4[u].x, hv.x, sacc); sacc = fmaf(wfc4[u].y, hv.y, sacc);
        sacc = fmaf(wfc4[u].z, hv.z, sacc); sacc = fmaf(wfc4[u].w, hv.w, sacc);
      }
      const float S = wave_sum(sacc);
      if (lane == 0) out[(size_t)(T_STEPS - 1) * NCH + lcol] = S + bfc_c;
    }
  }
}

extern "C" void kernel_launch(void* const* d_in, const int* in_sizes, int n_in,
                              void* d_out, int out_size, void* d_ws, size_t ws_size,
                              hipStream_t stream) {
  (void)in_sizes; (void)n_in; (void)out_size; (void)ws_size;
  const int* seq     = (const int*)d_in[0];
  const float* emb   = (const float*)d_in[1];
  const float* Wf    = (const float*)d_in[2];
  const float* bfv   = (const float*)d_in[3];
  const float* Wi    = (const float*)d_in[4];
  const float* biv   = (const float*)d_in[5];
  const float* Wg    = (const float*)d_in[6];
  const float* bgv   = (const float*)d_in[7];
  const float* Wo    = (const float*)d_in[8];
  const float* bov   = (const float*)d_in[9];
  const float* Wfc   = (const float*)d_in[10];
  const float* bfc   = (const float*)d_in[11];
  float* out         = (float*)d_out;
  unsigned long long* hbuf = (unsigned long long*)d_ws;   // 2*HID*8 = 32 KB

  hipMemsetAsync(d_ws, 0, 2 * HID * sizeof(unsigned long long), stream);

  void* args[] = {
    (void*)&seq, (void*)&emb,
    (void*)&Wf, (void*)&bfv, (void*)&Wi, (void*)&biv,
    (void*)&Wg, (void*)&bgv, (void*)&Wo, (void*)&bov,
    (void*)&Wfc, (void*)&bfc,
    (void*)&hbuf, (void*)&out
  };
  hipLaunchCooperativeKernel((const void*)lstm_persist, dim3(NBLK), dim3(TPB),
                             args, 0, stream);
}

// Round 7
// 62352.081 us; speedup vs baseline: 3.1297x; 3.1297x over previous
//
#include <hip/hip_runtime.h>
#include <stdint.h>

// CharLSTM persistent-RNN kernel for MI355X. f32 in / f32 out.
// R9:  conflict-free fragment layout; tagged 64-bit h words (f32<<32 | step).
// R10: flag hierarchy: -6.5% -> dependent-hop on saturated lines, refuted.
// R11: single-hop polling + x-dot overlap: neutral.
// R12: float4 fragments, ds_read_b128, DPP reduce, launch_bounds(512,2): -3%.
// R13: s_sleep(2) poll backoff + coalesced single-line publish: -41% (73->43ms).
//      Per-line service contention CONFIRMED binding.
// R14: 128x1024 shape: disaster (weight spill -> 170GB HBM). Shape pinned
//      to 512 thr/WG, launch_bounds(512,2).
// R15: 16B sc0-only asm polls: likely HANG (sc0 lacks agent coherence) and
//      the transaction math shows 16B loads don't reduce per-line pressure
//      anyway (wave coalescing already gives 1 transaction/WG/line/round).
//      LESSON: sync loads only via __hip_atomic_load.
// R16: two-level relay broadcast. Per-line pollers: hbuf 256 -> 8 (relay
//      WGs 0..7, tight spin), group buffers 31 each (s_sleep(1)). Relay
//      republishes raw tagged words -> consumers still get data+validity in
//      ONE dependent hop. De-saturates every line; the extra hop is cheap
//      (~600cyc) vs the ~3000cyc saturated service time it removes.

#define T_STEPS 16384
#define HID     2048
#define EMBD    512
#define NCH     128
#define FANIN   (EMBD + HID)
#define NBLK    256
#define TPB     512
#define NEUR_PER_WG 8
#define NGRP    8

static_assert(TPB == EMBD, "index math assumes TPB == EMBD");
static_assert(NBLK * NEUR_PER_WG == HID, "neuron coverage");

__device__ __forceinline__ float sigmoid_f(float x) {
  return 1.0f / (1.0f + __expf(-x));
}
__device__ __forceinline__ float tanh_f(float x) {
  return 1.0f - 2.0f / (__expf(2.0f * x) + 1.0f);
}
__device__ __forceinline__ unsigned long long ld_agent64(const unsigned long long* p) {
  return __hip_atomic_load(p, __ATOMIC_RELAXED, __HIP_MEMORY_SCOPE_AGENT);
}
__device__ __forceinline__ void st_agent64(unsigned long long* p, unsigned long long v) {
  __hip_atomic_store(p, v, __ATOMIC_RELAXED, __HIP_MEMORY_SCOPE_AGENT);
}

// ---- VALU-only wave64 reduction: DPP row_shr tree + readlane of row tails ----
#define DPP_ROW_SHR(n) (0x110 | (n))
__device__ __forceinline__ float row_reduce(float x) {
  x += __int_as_float(__builtin_amdgcn_update_dpp(0, __float_as_int(x), DPP_ROW_SHR(1), 0xF, 0xF, true));
  x += __int_as_float(__builtin_amdgcn_update_dpp(0, __float_as_int(x), DPP_ROW_SHR(2), 0xF, 0xF, true));
  x += __int_as_float(__builtin_amdgcn_update_dpp(0, __float_as_int(x), DPP_ROW_SHR(4), 0xF, 0xF, true));
  x += __int_as_float(__builtin_amdgcn_update_dpp(0, __float_as_int(x), DPP_ROW_SHR(8), 0xF, 0xF, true));
  return x;  // lanes 15/31/47/63 hold their row's sum
}
__device__ __forceinline__ float wave_sum(float x) {
  const int xi = __float_as_int(row_reduce(x));
  return __int_as_float(__builtin_amdgcn_readlane(xi, 15))
       + __int_as_float(__builtin_amdgcn_readlane(xi, 31))
       + __int_as_float(__builtin_amdgcn_readlane(xi, 47))
       + __int_as_float(__builtin_amdgcn_readlane(xi, 63));
}

__global__ __launch_bounds__(TPB, 2) void lstm_persist(
    const int* __restrict__ seq,
    const float* __restrict__ emb,
    const float* __restrict__ Wf, const float* __restrict__ bfv,
    const float* __restrict__ Wi, const float* __restrict__ biv,
    const float* __restrict__ Wg, const float* __restrict__ bgv,
    const float* __restrict__ Wo, const float* __restrict__ bov,
    const float* __restrict__ Wfc, const float* __restrict__ bfc,
    unsigned long long* __restrict__ hbuf,   // [2][HID] tagged h (producers)
    unsigned long long* __restrict__ gbuf,   // [NGRP][2][HID] relay copies
    float* __restrict__ out)                 // f32: [T][NCH] logits, h[HID], c[HID]
{
  __shared__ __attribute__((aligned(16))) float h_lds[2][HID];
  __shared__ float hout[NEUR_PER_WG];   // per-step collected neuron outputs

  const int tid  = threadIdx.x;
  const int wv   = tid >> 6;
  const int lane = tid & 63;
  const int j    = blockIdx.x * NEUR_PER_WG + wv;   // neuron this wave owns
  const int grp  = blockIdx.x & (NGRP - 1);
  const bool relay = (blockIdx.x < NGRP);           // WG g relays for group g

  // seq dtype guard (selects int32 on this data; kept for safety)
  int shift = 1;
  for (int k = 0; k < 64; ++k) {
    if (seq[2 * k + 1] != 0) { shift = 0; break; }
  }

  // ---- preload weights, float4 chunks: lane l owns cols {256k+4l..+3} ----
  const float* Wmat[4] = {Wf, Wi, Wg, Wo};
  const float* bvec[4] = {bfv, biv, bgv, bov};
  float4 wh4[4][8], wx4[4][2];
  float  bias[4];
  #pragma unroll
  for (int g = 0; g < 4; ++g) {
    const float* rp = Wmat[g] + (size_t)j * FANIN;
    const float4* hp4 = reinterpret_cast<const float4*>(rp + EMBD);
    const float4* xp4 = reinterpret_cast<const float4*>(rp);
    #pragma unroll
    for (int k = 0; k < 8; ++k) wh4[g][k] = hp4[k * 64 + lane];
    #pragma unroll
    for (int k = 0; k < 2; ++k) wx4[g][k] = xp4[k * 64 + lane];
    bias[g] = bvec[g][j];
  }

  // ---- logits duty: even WGs' wave 1 each own one output column ----
  int lcol = -1;
  float4 wfc4[8];
  float bfc_c = 0.0f;
  if (((blockIdx.x & 1) == 0) && wv == 1) {
    lcol = blockIdx.x >> 1;                 // 0..127
    const float4* wp4 = reinterpret_cast<const float4*>(Wfc + (size_t)lcol * HID);
    #pragma unroll
    for (int u = 0; u < 8; ++u) wfc4[u] = wp4[u * 64 + lane];
    bfc_c = bfc[lcol];
  }

  float creg = 0.0f;  // cell state (lane 0 only)
  const int i0 = tid, i1 = tid + TPB, i2 = tid + 2 * TPB, i3 = tid + 3 * TPB;

  for (int t = 0; t < T_STEPS; ++t) {
    const int bsel = t & 1;
    const unsigned ut = (unsigned)t;
    // relays poll the producer buffer; consumers poll their group's copy
    const unsigned long long* src = relay
        ? hbuf + (size_t)bsel * HID
        : gbuf + ((size_t)grp * 2 + bsel) * HID;

    // ---- issue the 4 tagged h loads first (outstanding during x work) ----
    unsigned long long v0 = ld_agent64(src + i0), v1 = ld_agent64(src + i1),
                       v2 = ld_agent64(src + i2), v3 = ld_agent64(src + i3);

    // ---- x loads (L2-resident emb row, float4 coalesced) ----
    const int s = seq[(size_t)t << shift];
    const float4* xr4 = reinterpret_cast<const float4*>(emb + (size_t)s * EMBD);
    const float4 xv0 = xr4[lane];
    const float4 xv1 = xr4[64 + lane];

    // ---- x-part of the gate dots: independent of h, hides h latency ----
    float a0 = 0.0f, a1 = 0.0f, a2 = 0.0f, a3 = 0.0f;
    #pragma unroll
    for (int k = 0; k < 2; ++k) {
      const float4 xv = (k == 0) ? xv0 : xv1;
      a0 = fmaf(wx4[0][k].x, xv.x, a0); a0 = fmaf(wx4[0][k].y, xv.y, a0);
      a0 = fmaf(wx4[0][k].z, xv.z, a0); a0 = fmaf(wx4[0][k].w, xv.w, a0);
      a1 = fmaf(wx4[1][k].x, xv.x, a1); a1 = fmaf(wx4[1][k].y, xv.y, a1);
      a1 = fmaf(wx4[1][k].z, xv.z, a1); a1 = fmaf(wx4[1][k].w, xv.w, a1);
      a2 = fmaf(wx4[2][k].x, xv.x, a2); a2 = fmaf(wx4[2][k].y, xv.y, a2);
      a2 = fmaf(wx4[2][k].z, xv.z, a2); a2 = fmaf(wx4[2][k].w, xv.w, a2);
      a3 = fmaf(wx4[3][k].x, xv.x, a3); a3 = fmaf(wx4[3][k].y, xv.y, a3);
      a3 = fmaf(wx4[3][k].z, xv.z, a3); a3 = fmaf(wx4[3][k].w, xv.w, a3);
    }

    // ---- readiness: relays tight-spin (8 pollers/line), consumers sleep ----
    while (((unsigned)v0 != ut) | ((unsigned)v1 != ut) |
           ((unsigned)v2 != ut) | ((unsigned)v3 != ut)) {
      if (!relay) __builtin_amdgcn_s_sleep(1);
      if ((unsigned)v0 != ut) v0 = ld_agent64(src + i0);
      if ((unsigned)v1 != ut) v1 = ld_agent64(src + i1);
      if ((unsigned)v2 != ut) v2 = ld_agent64(src + i2);
      if ((unsigned)v3 != ut) v3 = ld_agent64(src + i3);
    }

    // ---- relay republish (raw tagged words) before own compute ----
    if (relay) {
      unsigned long long* dst = gbuf + ((size_t)grp * 2 + bsel) * HID;
      st_agent64(dst + i0, v0); st_agent64(dst + i1, v1);
      st_agent64(dst + i2, v2); st_agent64(dst + i3, v3);
    }

    h_lds[bsel][i0] = __uint_as_float((unsigned)(v0 >> 32));
    h_lds[bsel][i1] = __uint_as_float((unsigned)(v1 >> 32));
    h_lds[bsel][i2] = __uint_as_float((unsigned)(v2 >> 32));
    h_lds[bsel][i3] = __uint_as_float((unsigned)(v3 >> 32));
    __syncthreads();

    // ---- h-part of the gate dots: 8x ds_read_b128, conflict-free ----
    const float4* hp4 = reinterpret_cast<const float4*>(&h_lds[bsel][0]);
    #pragma unroll
    for (int k = 0; k < 8; ++k) {
      const float4 hv = hp4[k * 64 + lane];
      a0 = fmaf(wh4[0][k].x, hv.x, a0); a0 = fmaf(wh4[0][k].y, hv.y, a0);
      a0 = fmaf(wh4[0][k].z, hv.z, a0); a0 = fmaf(wh4[0][k].w, hv.w, a0);
      a1 = fmaf(wh4[1][k].x, hv.x, a1); a1 = fmaf(wh4[1][k].y, hv.y, a1);
      a1 = fmaf(wh4[1][k].z, hv.z, a1); a1 = fmaf(wh4[1][k].w, hv.w, a1);
      a2 = fmaf(wh4[2][k].x, hv.x, a2); a2 = fmaf(wh4[2][k].y, hv.y, a2);
      a2 = fmaf(wh4[2][k].z, hv.z, a2); a2 = fmaf(wh4[2][k].w, hv.w, a2);
      a3 = fmaf(wh4[3][k].x, hv.x, a3); a3 = fmaf(wh4[3][k].y, hv.y, a3);
      a3 = fmaf(wh4[3][k].z, hv.z, a3); a3 = fmaf(wh4[3][k].w, hv.w, a3);
    }

    // ---- VALU-only reduction (no DS-pipe shfl) ----
    const float A0 = wave_sum(a0);
    const float A1 = wave_sum(a1);
    const float A2 = wave_sum(a2);
    const float A3 = wave_sum(a3);

    if (lane == 0) {
      const float fg = sigmoid_f(A0 + bias[0]);
      const float ig = sigmoid_f(A1 + bias[1]);
      const float gg = tanh_f(A2 + bias[2]);
      const float og = sigmoid_f(A3 + bias[3]);
      creg = fg * creg + ig * gg;
      const float hn = og * tanh_f(creg);
      hout[wv] = hn;                          // collect for coalesced publish
      if (t == T_STEPS - 1) {
        out[(size_t)T_STEPS * NCH + j]       = hn;     // final h
        out[(size_t)T_STEPS * NCH + HID + j] = creg;   // final c
      }
    }
    __syncthreads();   // hout[] complete

    // ---- coalesced publish: ONE 64B line store by wave 0 lanes 0..7 ----
    if (wv == 0 && lane < NEUR_PER_WG) {
      const unsigned long long pk =
          ((unsigned long long)__float_as_uint(hout[lane]) << 32) |
          (unsigned long long)(unsigned)(t + 1);
      st_agent64(&hbuf[(size_t)((t + 1) & 1) * HID +
                       (size_t)blockIdx.x * NEUR_PER_WG + lane], pk);
    }

    // ---- logits for step t-1 from already-staged h[t] (rides in wait slack) ----
    if (lcol >= 0 && t > 0) {
      const float4* hq4 = reinterpret_cast<const float4*>(&h_lds[bsel][0]);
      float sacc = 0.0f;
      #pragma unroll
      for (int u = 0; u < 8; ++u) {
        const float4 hv = hq4[u * 64 + lane];
        sacc = fmaf(wfc4[u].x, hv.x, sacc); sacc = fmaf(wfc4[u].y, hv.y, sacc);
        sacc = fmaf(wfc4[u].z, hv.z, sacc); sacc = fmaf(wfc4[u].w, hv.w, sacc);
      }
      const float S = wave_sum(sacc);
      if (lane == 0) out[(size_t)(t - 1) * NCH + lcol] = S + bfc_c;
    }
  }

  // ---- epilogue: stage h[T] (tag T, slot 0) and emit logits for t = T-1 ----
  {
    const unsigned ut = (unsigned)T_STEPS;
    const unsigned long long* src = relay ? hbuf
                                          : gbuf + (size_t)grp * 2 * HID;
    unsigned long long v0 = ld_agent64(src + i0), v1 = ld_agent64(src + i1),
                       v2 = ld_agent64(src + i2), v3 = ld_agent64(src + i3);
    while (((unsigned)v0 != ut) | ((unsigned)v1 != ut) |
           ((unsigned)v2 != ut) | ((unsigned)v3 != ut)) {
      if (!relay) __builtin_amdgcn_s_sleep(1);
      if ((unsigned)v0 != ut) v0 = ld_agent64(src + i0);
      if ((unsigned)v1 != ut) v1 = ld_agent64(src + i1);
      if ((unsigned)v2 != ut) v2 = ld_agent64(src + i2);
      if ((unsigned)v3 != ut) v3 = ld_agent64(src + i3);
    }
    if (relay) {
      unsigned long long* dst = gbuf + (size_t)grp * 2 * HID;
      st_agent64(dst + i0, v0); st_agent64(dst + i1, v1);
      st_agent64(dst + i2, v2); st_agent64(dst + i3, v3);
    }
    h_lds[0][i0] = __uint_as_float((unsigned)(v0 >> 32));
    h_lds[0][i1] = __uint_as_float((unsigned)(v1 >> 32));
    h_lds[0][i2] = __uint_as_float((unsigned)(v2 >> 32));
    h_lds[0][i3] = __uint_as_float((unsigned)(v3 >> 32));
    __syncthreads();
    if (lcol >= 0) {
      const float4* hq4 = reinterpret_cast<const float4*>(&h_lds[0][0]);
      float sacc = 0.0f;
      #pragma unroll
      for (int u = 0; u < 8; ++u) {
        const float4 hv = hq4[u * 64 + lane];
        sacc = fmaf(wfc4[u].x, hv.x, sacc); sacc = fmaf(wfc4[u].y, hv.y, sacc);
        sacc = fmaf(wfc4[u].z, hv.z, sacc); sacc = fmaf(wfc4[u].w, hv.w, sacc);
      }
      const float S = wave_sum(sacc);
      if (lane == 0) out[(size_t)(T_STEPS - 1) * NCH + lcol] = S + bfc_c;
    }
  }
}

extern "C" void kernel_launch(void* const* d_in, const int* in_sizes, int n_in,
                              void* d_out, int out_size, void* d_ws, size_t ws_size,
                              hipStream_t stream) {
  (void)in_sizes; (void)n_in; (void)out_size; (void)ws_size;
  const int* seq     = (const int*)d_in[0];
  const float* emb   = (const float*)d_in[1];
  const float* Wf    = (const float*)d_in[2];
  const float* bfv   = (const float*)d_in[3];
  const float* Wi    = (const float*)d_in[4];
  const float* biv   = (const float*)d_in[5];
  const float* Wg    = (const float*)d_in[6];
  const float* bgv   = (const float*)d_in[7];
  const float* Wo    = (const float*)d_in[8];
  const float* bov   = (const float*)d_in[9];
  const float* Wfc   = (const float*)d_in[10];
  const float* bfc   = (const float*)d_in[11];
  float* out         = (float*)d_out;
  unsigned long long* hbuf = (unsigned long long*)d_ws;                 // 32 KB
  unsigned long long* gbuf = hbuf + 2 * HID;                            // 8*32 KB

  hipMemsetAsync(d_ws, 0,
                 (size_t)(1 + NGRP) * 2 * HID * sizeof(unsigned long long),
                 stream);

  void* args[] = {
    (void*)&seq, (void*)&emb,
    (void*)&Wf, (void*)&bfv, (void*)&Wi, (void*)&biv,
    (void*)&Wg, (void*)&bgv, (void*)&Wo, (void*)&bov,
    (void*)&Wfc, (void*)&bfc,
    (void*)&hbuf, (void*)&gbuf, (void*)&out
  };
  hipLaunchCooperativeKernel((const void*)lstm_persist, dim3(NBLK), dim3(TPB),
                             args, 0, stream);
}

// Round 8
// 45404.355 us; speedup vs baseline: 4.2980x; 1.3733x over previous
//
#include <hip/hip_runtime.h>
#include <stdint.h>

// CharLSTM persistent-RNN kernel for MI355X. f32 in / f32 out.
// R9:  conflict-free fragment layout; tagged 64-bit h words (f32<<32 | step).
// R10: flag hierarchy: -6.5% -> dependent hop, refuted.
// R11: single-hop polling + x-dot overlap: neutral.
// R12: float4 fragments, ds_read_b128, DPP reduce: -3%.
// R13: s_sleep(2) poll backoff + coalesced single-line publish: -41% (43.2ms).
// R14: 1024-thr shape: disaster (spill->HBM). Shape pinned 512thr.
// R15: sc0-only asm polls: hang risk; wave-coalescing makes 16B polls moot.
// R16: relay broadcast: WORSE (+19ms = +1 LLC hop). Poll-storm theory dead
//      at R13's operating point; the invariant cost is elsewhere.
// R17: the invariant was under our nose all along: VGPR_Count=124 < 160
//      declared weight floats in EVERY round. launch_bounds' 2nd arg only
//      sets a MINIMUM occupancy; the compiler budgeted 128 VGPR and SANK the
//      weight loads into the t-loop -- re-fetching ~100 floats/thread/step
//      from per-XCD L2 (invisible in FETCH_SIZE). Fix:
//        (a) amdgpu_waves_per_eu(2,2): budget for exactly 2 waves/EU
//            (our true occupancy) -> 256 VGPR cap.
//        (b) opaque-pin every weight register (asm "+v") after preload so
//            the loads cannot be rematerialized into the loop.
//      Everything else identical to R13.

#define T_STEPS 16384
#define HID     2048
#define EMBD    512
#define NCH     128
#define FANIN   (EMBD + HID)
#define NBLK    256
#define TPB     512
#define NEUR_PER_WG 8

static_assert(TPB == EMBD, "index math assumes TPB == EMBD");
static_assert(NBLK * NEUR_PER_WG == HID, "neuron coverage");

__device__ __forceinline__ float sigmoid_f(float x) {
  return 1.0f / (1.0f + __expf(-x));
}
__device__ __forceinline__ float tanh_f(float x) {
  return 1.0f - 2.0f / (__expf(2.0f * x) + 1.0f);
}
__device__ __forceinline__ unsigned long long ld_agent64(const unsigned long long* p) {
  return __hip_atomic_load(p, __ATOMIC_RELAXED, __HIP_MEMORY_SCOPE_AGENT);
}
__device__ __forceinline__ void st_agent64(unsigned long long* p, unsigned long long v) {
  __hip_atomic_store(p, v, __ATOMIC_RELAXED, __HIP_MEMORY_SCOPE_AGENT);
}

// Opaque register pin: value origin becomes unknown to the optimizer, so it
// must stay live in VGPRs (prevents load rematerialization into the loop).
__device__ __forceinline__ void pin_f(float& x) {
  asm volatile("" : "+v"(x));
}
__device__ __forceinline__ void pin4(float4& v) {
  asm volatile("" : "+v"(v.x), "+v"(v.y), "+v"(v.z), "+v"(v.w));
}

// ---- VALU-only wave64 reduction: DPP row_shr tree + readlane of row tails ----
#define DPP_ROW_SHR(n) (0x110 | (n))
__device__ __forceinline__ float row_reduce(float x) {
  x += __int_as_float(__builtin_amdgcn_update_dpp(0, __float_as_int(x), DPP_ROW_SHR(1), 0xF, 0xF, true));
  x += __int_as_float(__builtin_amdgcn_update_dpp(0, __float_as_int(x), DPP_ROW_SHR(2), 0xF, 0xF, true));
  x += __int_as_float(__builtin_amdgcn_update_dpp(0, __float_as_int(x), DPP_ROW_SHR(4), 0xF, 0xF, true));
  x += __int_as_float(__builtin_amdgcn_update_dpp(0, __float_as_int(x), DPP_ROW_SHR(8), 0xF, 0xF, true));
  return x;  // lanes 15/31/47/63 hold their row's sum
}
__device__ __forceinline__ float wave_sum(float x) {
  const int xi = __float_as_int(row_reduce(x));
  return __int_as_float(__builtin_amdgcn_readlane(xi, 15))
       + __int_as_float(__builtin_amdgcn_readlane(xi, 31))
       + __int_as_float(__builtin_amdgcn_readlane(xi, 47))
       + __int_as_float(__builtin_amdgcn_readlane(xi, 63));
}

__global__ __launch_bounds__(TPB)
__attribute__((amdgpu_waves_per_eu(2, 2)))
void lstm_persist(
    const int* __restrict__ seq,
    const float* __restrict__ emb,
    const float* __restrict__ Wf, const float* __restrict__ bfv,
    const float* __restrict__ Wi, const float* __restrict__ biv,
    const float* __restrict__ Wg, const float* __restrict__ bgv,
    const float* __restrict__ Wo, const float* __restrict__ bov,
    const float* __restrict__ Wfc, const float* __restrict__ bfc,
    unsigned long long* __restrict__ hbuf,   // [2][HID] tagged h
    float* __restrict__ out)                 // f32: [T][NCH] logits, h[HID], c[HID]
{
  __shared__ __attribute__((aligned(16))) float h_lds[2][HID];
  __shared__ float hout[NEUR_PER_WG];   // per-step collected neuron outputs

  const int tid  = threadIdx.x;
  const int wv   = tid >> 6;
  const int lane = tid & 63;
  const int j    = blockIdx.x * NEUR_PER_WG + wv;   // neuron this wave owns

  // seq dtype guard (selects int32 on this data; kept for safety)
  int shift = 1;
  for (int k = 0; k < 64; ++k) {
    if (seq[2 * k + 1] != 0) { shift = 0; break; }
  }

  // ---- preload weights, float4 chunks: lane l owns cols {256k+4l..+3} ----
  const float* Wmat[4] = {Wf, Wi, Wg, Wo};
  const float* bvec[4] = {bfv, biv, bgv, bov};
  float4 wh4[4][8], wx4[4][2];
  float  bias[4];
  #pragma unroll
  for (int g = 0; g < 4; ++g) {
    const float* rp = Wmat[g] + (size_t)j * FANIN;
    const float4* hp4 = reinterpret_cast<const float4*>(rp + EMBD);
    const float4* xp4 = reinterpret_cast<const float4*>(rp);
    #pragma unroll
    for (int k = 0; k < 8; ++k) wh4[g][k] = hp4[k * 64 + lane];
    #pragma unroll
    for (int k = 0; k < 2; ++k) wx4[g][k] = xp4[k * 64 + lane];
    bias[g] = bvec[g][j];
  }
  // pin weights into registers: loads must not sink into the t-loop
  #pragma unroll
  for (int g = 0; g < 4; ++g) {
    #pragma unroll
    for (int k = 0; k < 8; ++k) pin4(wh4[g][k]);
    #pragma unroll
    for (int k = 0; k < 2; ++k) pin4(wx4[g][k]);
    pin_f(bias[g]);
  }

  // ---- logits duty: even WGs' wave 1 each own one output column ----
  int lcol = -1;
  float4 wfc4[8];
  float bfc_c = 0.0f;
  if (((blockIdx.x & 1) == 0) && wv == 1) {
    lcol = blockIdx.x >> 1;                 // 0..127
    const float4* wp4 = reinterpret_cast<const float4*>(Wfc + (size_t)lcol * HID);
    #pragma unroll
    for (int u = 0; u < 8; ++u) { wfc4[u] = wp4[u * 64 + lane]; pin4(wfc4[u]); }
    bfc_c = bfc[lcol];
    pin_f(bfc_c);
  }

  float creg = 0.0f;  // cell state (lane 0 only)
  const int i0 = tid, i1 = tid + TPB, i2 = tid + 2 * TPB, i3 = tid + 3 * TPB;

  for (int t = 0; t < T_STEPS; ++t) {
    const int bsel = t & 1;
    const unsigned long long* src = hbuf + (size_t)bsel * HID;
    const unsigned ut = (unsigned)t;

    // ---- issue the 4 tagged h loads first (outstanding during x work) ----
    unsigned long long v0 = ld_agent64(src + i0), v1 = ld_agent64(src + i1),
                       v2 = ld_agent64(src + i2), v3 = ld_agent64(src + i3);

    // ---- x loads (L2-resident emb row, float4 coalesced) ----
    const int s = seq[(size_t)t << shift];
    const float4* xr4 = reinterpret_cast<const float4*>(emb + (size_t)s * EMBD);
    const float4 xv0 = xr4[lane];
    const float4 xv1 = xr4[64 + lane];

    // ---- x-part of the gate dots: independent of h, hides h latency ----
    float a0 = 0.0f, a1 = 0.0f, a2 = 0.0f, a3 = 0.0f;
    #pragma unroll
    for (int k = 0; k < 2; ++k) {
      const float4 xv = (k == 0) ? xv0 : xv1;
      a0 = fmaf(wx4[0][k].x, xv.x, a0); a0 = fmaf(wx4[0][k].y, xv.y, a0);
      a0 = fmaf(wx4[0][k].z, xv.z, a0); a0 = fmaf(wx4[0][k].w, xv.w, a0);
      a1 = fmaf(wx4[1][k].x, xv.x, a1); a1 = fmaf(wx4[1][k].y, xv.y, a1);
      a1 = fmaf(wx4[1][k].z, xv.z, a1); a1 = fmaf(wx4[1][k].w, xv.w, a1);
      a2 = fmaf(wx4[2][k].x, xv.x, a2); a2 = fmaf(wx4[2][k].y, xv.y, a2);
      a2 = fmaf(wx4[2][k].z, xv.z, a2); a2 = fmaf(wx4[2][k].w, xv.w, a2);
      a3 = fmaf(wx4[3][k].x, xv.x, a3); a3 = fmaf(wx4[3][k].y, xv.y, a3);
      a3 = fmaf(wx4[3][k].z, xv.z, a3); a3 = fmaf(wx4[3][k].w, xv.w, a3);
    }

    // ---- single-hop readiness with s_sleep backoff ----
    while (((unsigned)v0 != ut) | ((unsigned)v1 != ut) |
           ((unsigned)v2 != ut) | ((unsigned)v3 != ut)) {
      __builtin_amdgcn_s_sleep(2);   // keep per-line request rate low
      if ((unsigned)v0 != ut) v0 = ld_agent64(src + i0);
      if ((unsigned)v1 != ut) v1 = ld_agent64(src + i1);
      if ((unsigned)v2 != ut) v2 = ld_agent64(src + i2);
      if ((unsigned)v3 != ut) v3 = ld_agent64(src + i3);
    }
    h_lds[bsel][i0] = __uint_as_float((unsigned)(v0 >> 32));
    h_lds[bsel][i1] = __uint_as_float((unsigned)(v1 >> 32));
    h_lds[bsel][i2] = __uint_as_float((unsigned)(v2 >> 32));
    h_lds[bsel][i3] = __uint_as_float((unsigned)(v3 >> 32));
    __syncthreads();

    // ---- h-part of the gate dots: 8x ds_read_b128, conflict-free ----
    const float4* hp4 = reinterpret_cast<const float4*>(&h_lds[bsel][0]);
    #pragma unroll
    for (int k = 0; k < 8; ++k) {
      const float4 hv = hp4[k * 64 + lane];
      a0 = fmaf(wh4[0][k].x, hv.x, a0); a0 = fmaf(wh4[0][k].y, hv.y, a0);
      a0 = fmaf(wh4[0][k].z, hv.z, a0); a0 = fmaf(wh4[0][k].w, hv.w, a0);
      a1 = fmaf(wh4[1][k].x, hv.x, a1); a1 = fmaf(wh4[1][k].y, hv.y, a1);
      a1 = fmaf(wh4[1][k].z, hv.z, a1); a1 = fmaf(wh4[1][k].w, hv.w, a1);
      a2 = fmaf(wh4[2][k].x, hv.x, a2); a2 = fmaf(wh4[2][k].y, hv.y, a2);
      a2 = fmaf(wh4[2][k].z, hv.z, a2); a2 = fmaf(wh4[2][k].w, hv.w, a2);
      a3 = fmaf(wh4[3][k].x, hv.x, a3); a3 = fmaf(wh4[3][k].y, hv.y, a3);
      a3 = fmaf(wh4[3][k].z, hv.z, a3); a3 = fmaf(wh4[3][k].w, hv.w, a3);
    }

    // ---- VALU-only reduction (no DS-pipe shfl) ----
    const float A0 = wave_sum(a0);
    const float A1 = wave_sum(a1);
    const float A2 = wave_sum(a2);
    const float A3 = wave_sum(a3);

    if (lane == 0) {
      const float fg = sigmoid_f(A0 + bias[0]);
      const float ig = sigmoid_f(A1 + bias[1]);
      const float gg = tanh_f(A2 + bias[2]);
      const float og = sigmoid_f(A3 + bias[3]);
      creg = fg * creg + ig * gg;
      const float hn = og * tanh_f(creg);
      hout[wv] = hn;                          // collect for coalesced publish
      if (t == T_STEPS - 1) {
        out[(size_t)T_STEPS * NCH + j]       = hn;     // final h
        out[(size_t)T_STEPS * NCH + HID + j] = creg;   // final c
      }
    }
    __syncthreads();   // hout[] complete

    // ---- coalesced publish: ONE 64B line store by wave 0 lanes 0..7 ----
    if (wv == 0 && lane < NEUR_PER_WG) {
      const unsigned long long pk =
          ((unsigned long long)__float_as_uint(hout[lane]) << 32) |
          (unsigned long long)(unsigned)(t + 1);
      st_agent64(&hbuf[(size_t)((t + 1) & 1) * HID +
                       (size_t)blockIdx.x * NEUR_PER_WG + lane], pk);
    }

    // ---- logits for step t-1 from already-staged h[t] (rides in wait slack) ----
    if (lcol >= 0 && t > 0) {
      const float4* hq4 = reinterpret_cast<const float4*>(&h_lds[bsel][0]);
      float sacc = 0.0f;
      #pragma unroll
      for (int u = 0; u < 8; ++u) {
        const float4 hv = hq4[u * 64 + lane];
        sacc = fmaf(wfc4[u].x, hv.x, sacc); sacc = fmaf(wfc4[u].y, hv.y, sacc);
        sacc = fmaf(wfc4[u].z, hv.z, sacc); sacc = fmaf(wfc4[u].w, hv.w, sacc);
      }
      const float S = wave_sum(sacc);
      if (lane == 0) out[(size_t)(t - 1) * NCH + lcol] = S + bfc_c;
    }
  }

  // ---- epilogue: stage h[T] (tag T, slot 0) and emit logits for t = T-1 ----
  {
    const unsigned long long* src = hbuf;  // T_STEPS & 1 == 0
    const unsigned ut = (unsigned)T_STEPS;
    unsigned long long v0 = ld_agent64(src + i0), v1 = ld_agent64(src + i1),
                       v2 = ld_agent64(src + i2), v3 = ld_agent64(src + i3);
    while (((unsigned)v0 != ut) | ((unsigned)v1 != ut) |
           ((unsigned)v2 != ut) | ((unsigned)v3 != ut)) {
      __builtin_amdgcn_s_sleep(2);
      if ((unsigned)v0 != ut) v0 = ld_agent64(src + i0);
      if ((unsigned)v1 != ut) v1 = ld_agent64(src + i1);
      if ((unsigned)v2 != ut) v2 = ld_agent64(src + i2);
      if ((unsigned)v3 != ut) v3 = ld_agent64(src + i3);
    }
    h_lds[0][i0] = __uint_as_float((unsigned)(v0 >> 32));
    h_lds[0][i1] = __uint_as_float((unsigned)(v1 >> 32));
    h_lds[0][i2] = __uint_as_float((unsigned)(v2 >> 32));
    h_lds[0][i3] = __uint_as_float((unsigned)(v3 >> 32));
    __syncthreads();
    if (lcol >= 0) {
      const float4* hq4 = reinterpret_cast<const float4*>(&h_lds[0][0]);
      float sacc = 0.0f;
      #pragma unroll
      for (int u = 0; u < 8; ++u) {
        const float4 hv = hq4[u * 64 + lane];
        sacc = fmaf(wfc4[u].x, hv.x, sacc); sacc = fmaf(wfc4[u].y, hv.y, sacc);
        sacc = fmaf(wfc4[u].z, hv.z, sacc); sacc = fmaf(wfc4[u].w, hv.w, sacc);
      }
      const float S = wave_sum(sacc);
      if (lane == 0) out[(size_t)(T_STEPS - 1) * NCH + lcol] = S + bfc_c;
    }
  }
}

extern "C" void kernel_launch(void* const* d_in, const int* in_sizes, int n_in,
                              void* d_out, int out_size, void* d_ws, size_t ws_size,
                              hipStream_t stream) {
  (void)in_sizes; (void)n_in; (void)out_size; (void)ws_size;
  const int* seq     = (const int*)d_in[0];
  const float* emb   = (const float*)d_in[1];
  const float* Wf    = (const float*)d_in[2];
  const float* bfv   = (const float*)d_in[3];
  const float* Wi    = (const float*)d_in[4];
  const float* biv   = (const float*)d_in[5];
  const float* Wg    = (const float*)d_in[6];
  const float* bgv   = (const float*)d_in[7];
  const float* Wo    = (const float*)d_in[8];
  const float* bov   = (const float*)d_in[9];
  const float* Wfc   = (const float*)d_in[10];
  const float* bfc   = (const float*)d_in[11];
  float* out         = (float*)d_out;
  unsigned long long* hbuf = (unsigned long long*)d_ws;   // 2*HID*8 = 32 KB

  hipMemsetAsync(d_ws, 0, 2 * HID * sizeof(unsigned long long), stream);

  void* args[] = {
    (void*)&seq, (void*)&emb,
    (void*)&Wf, (void*)&bfv, (void*)&Wi, (void*)&biv,
    (void*)&Wg, (void*)&bgv, (void*)&Wo, (void*)&bov,
    (void*)&Wfc, (void*)&bfc,
    (void*)&hbuf, (void*)&out
  };
  hipLaunchCooperativeKernel((const void*)lstm_persist, dim3(NBLK), dim3(TPB),
                             args, 0, stream);
}